// Round 4
// baseline (103.662 us; speedup 1.0000x reference)
//
#include <hip/hip_runtime.h>
#include <math.h>

#define DIM 256
#define NUM_EMB 1024
#define ROWS 16384
#define NUMEL 4194304.0f   // 8*2048*256

typedef __attribute__((ext_vector_type(8))) short bf16x8;
typedef __attribute__((ext_vector_type(4))) float f32x4;

// f32 -> bf16 round-to-nearest-even (bit pattern)
__device__ __forceinline__ unsigned short f2bf(float f) {
    unsigned int u = __float_as_uint(f);
    u = (u + 0x7FFFu + ((u >> 16) & 1u)) >> 16;
    return (unsigned short)u;
}

// ws layout (bytes):
//   Ebf : [0,      524288)  bf16 codebook, fragment-linear:
//         subtile t=row/16, kc=dim/32 -> 1024B block; lane l=16g+r holds
//         row t*16+r, dims [kc*32+8g,+8) at ushort off (t*8+kc)*512 + l*8
//   esq : [524288, 528384)  f32 [1024] codebook row norms (exact)
//   bsum: [528384, 529408)  f32 [256]  per-block loss partials

// ---- kprepE: codebook f32 -> fragment-linear bf16 + exact sq-norms ----
__global__ __launch_bounds__(256) void kprepE(
        const float* __restrict__ src, unsigned short* __restrict__ dst,
        float* __restrict__ sq) {
    int t = blockIdx.x * 4 + (threadIdx.x >> 6);
    int l = threadIdx.x & 63;
    int r = l & 15, g = l >> 4;
    const float* rp = src + (t * 16 + r) * DIM + g * 8;
    float s = 0.f;
    #pragma unroll
    for (int kc = 0; kc < 8; ++kc) {
        float4 v0 = *(const float4*)(rp + kc * 32);
        float4 v1 = *(const float4*)(rp + kc * 32 + 4);
        bf16x8 o;
        o[0] = f2bf(v0.x); o[1] = f2bf(v0.y); o[2] = f2bf(v0.z); o[3] = f2bf(v0.w);
        o[4] = f2bf(v1.x); o[5] = f2bf(v1.y); o[6] = f2bf(v1.z); o[7] = f2bf(v1.w);
        *(bf16x8*)(dst + (t * 8 + kc) * 512 + l * 8) = o;
        s += v0.x*v0.x + v0.y*v0.y + v0.z*v0.z + v0.w*v0.w
           + v1.x*v1.x + v1.y*v1.y + v1.z*v1.z + v1.w*v1.w;
    }
    s += __shfl_xor(s, 16);
    s += __shfl_xor(s, 32);
    if (g == 0) sq[t * 16 + r] = s;
}

// ---- k1: fused X-convert + argmin + gather + loss partial -------------
// 512 threads = 8 waves; block owns 64 X rows; wave w streams codebook
// chunk [w*128, +128) against all 4 M-subtiles (A in registers from LDS).
__global__ __launch_bounds__(512, 2) void k1_main(
        const float* __restrict__ X,
        const unsigned short* __restrict__ Ebf,
        const float* __restrict__ esq,
        const float* __restrict__ E,
        float* __restrict__ outq, float* __restrict__ bsum) {
    __shared__ unsigned short Af[4][8][512];   // 32 KB: A frags, frag-linear
    __shared__ float sxsq[64];
    __shared__ float sval[8][64];
    __shared__ int   sidx[8][64];
    __shared__ float sloss[64];
    __shared__ int   sfin[64];

    int tid  = threadIdx.x;
    int wid  = tid >> 6;
    int lane = tid & 63;
    int r15  = lane & 15;
    int g    = lane >> 4;
    int m0   = blockIdx.x * 64;

    // ---- phase 1: X f32 (coalesced) -> bf16 frags in LDS + row norms ----
    {
        int half = tid >> 5;          // row within 16-row subtile
        int q    = tid & 31;          // dim group (8 dims)
        int kcw  = q >> 2;
        int gw   = q & 3;
        int lw   = gw * 16 + half;
        #pragma unroll
        for (int p = 0; p < 4; ++p) {
            int r = p * 16 + half;
            const float* rp = X + (m0 + r) * DIM + q * 8;
            float4 v0 = *(const float4*)rp;
            float4 v1 = *(const float4*)(rp + 4);
            bf16x8 o;
            o[0] = f2bf(v0.x); o[1] = f2bf(v0.y); o[2] = f2bf(v0.z); o[3] = f2bf(v0.w);
            o[4] = f2bf(v1.x); o[5] = f2bf(v1.y); o[6] = f2bf(v1.z); o[7] = f2bf(v1.w);
            *(bf16x8*)&Af[p][kcw][lw * 8] = o;
            float s = v0.x*v0.x + v0.y*v0.y + v0.z*v0.z + v0.w*v0.w
                    + v1.x*v1.x + v1.y*v1.y + v1.z*v1.z + v1.w*v1.w;
            #pragma unroll
            for (int m = 1; m <= 16; m <<= 1) s += __shfl_xor(s, m);
            if (q == 0) sxsq[r] = s;
        }
    }
    __syncthreads();

    // ---- phase 2: A frags -> registers, stream codebook chunk ----
    bf16x8 a0[8], a1[8], a2[8], a3[8];
    #pragma unroll
    for (int kc = 0; kc < 8; ++kc) {
        a0[kc] = *(const bf16x8*)&Af[0][kc][lane * 8];
        a1[kc] = *(const bf16x8*)&Af[1][kc][lane * 8];
        a2[kc] = *(const bf16x8*)&Af[2][kc][lane * 8];
        a3[kc] = *(const bf16x8*)&Af[3][kc][lane * 8];
    }

    float bv0[4] = {INFINITY,INFINITY,INFINITY,INFINITY};
    float bv1[4] = {INFINITY,INFINITY,INFINITY,INFINITY};
    float bv2[4] = {INFINITY,INFINITY,INFINITY,INFINITY};
    float bv3[4] = {INFINITY,INFINITY,INFINITY,INFINITY};
    int   bi0[4] = {0,0,0,0}, bi1[4] = {0,0,0,0};
    int   bi2[4] = {0,0,0,0}, bi3[4] = {0,0,0,0};

    #pragma unroll
    for (int ns = 0; ns < 8; ++ns) {
        int te = wid * 8 + ns;
        const unsigned short* eb = Ebf + te * 4096 + lane * 8;
        bf16x8 b[8];
        #pragma unroll
        for (int kc = 0; kc < 8; ++kc)
            b[kc] = *(const bf16x8*)(eb + kc * 512);
        float es = esq[te * 16 + r15];
        f32x4 c0 = {0.f,0.f,0.f,0.f}, c1 = {0.f,0.f,0.f,0.f};
        f32x4 c2 = {0.f,0.f,0.f,0.f}, c3 = {0.f,0.f,0.f,0.f};
        #pragma unroll
        for (int kc = 0; kc < 8; ++kc) {
            c0 = __builtin_amdgcn_mfma_f32_16x16x32_bf16(a0[kc], b[kc], c0, 0, 0, 0);
            c1 = __builtin_amdgcn_mfma_f32_16x16x32_bf16(a1[kc], b[kc], c1, 0, 0, 0);
            c2 = __builtin_amdgcn_mfma_f32_16x16x32_bf16(a2[kc], b[kc], c2, 0, 0, 0);
            c3 = __builtin_amdgcn_mfma_f32_16x16x32_bf16(a3[kc], b[kc], c3, 0, 0, 0);
        }
        int brow = te * 16 + r15;
        #pragma unroll
        for (int r = 0; r < 4; ++r) {
            float v;
            v = fmaf(-2.f, c0[r], es); if (v < bv0[r]) { bv0[r] = v; bi0[r] = brow; }
            v = fmaf(-2.f, c1[r], es); if (v < bv1[r]) { bv1[r] = v; bi1[r] = brow; }
            v = fmaf(-2.f, c2[r], es); if (v < bv2[r]) { bv2[r] = v; bi2[r] = brow; }
            v = fmaf(-2.f, c3[r], es); if (v < bv3[r]) { bv3[r] = v; bi3[r] = brow; }
        }
    }

    // per-wave argmin across the 16 lanes of each row-group
    #pragma unroll
    for (int m = 1; m <= 8; m <<= 1) {
        #pragma unroll
        for (int r = 0; r < 4; ++r) {
            float ov; int oi;
            ov = __shfl_xor(bv0[r], m); oi = __shfl_xor(bi0[r], m);
            if (ov < bv0[r] || (ov == bv0[r] && oi < bi0[r])) { bv0[r] = ov; bi0[r] = oi; }
            ov = __shfl_xor(bv1[r], m); oi = __shfl_xor(bi1[r], m);
            if (ov < bv1[r] || (ov == bv1[r] && oi < bi1[r])) { bv1[r] = ov; bi1[r] = oi; }
            ov = __shfl_xor(bv2[r], m); oi = __shfl_xor(bi2[r], m);
            if (ov < bv2[r] || (ov == bv2[r] && oi < bi2[r])) { bv2[r] = ov; bi2[r] = oi; }
            ov = __shfl_xor(bv3[r], m); oi = __shfl_xor(bi3[r], m);
            if (ov < bv3[r] || (ov == bv3[r] && oi < bi3[r])) { bv3[r] = ov; bi3[r] = oi; }
        }
    }
    if (r15 == 0) {
        #pragma unroll
        for (int r = 0; r < 4; ++r) {
            sval[wid][ 0 + g * 4 + r] = bv0[r];  sidx[wid][ 0 + g * 4 + r] = bi0[r];
            sval[wid][16 + g * 4 + r] = bv1[r];  sidx[wid][16 + g * 4 + r] = bi1[r];
            sval[wid][32 + g * 4 + r] = bv2[r];  sidx[wid][32 + g * 4 + r] = bi2[r];
            sval[wid][48 + g * 4 + r] = bv3[r];  sidx[wid][48 + g * 4 + r] = bi3[r];
        }
    }
    __syncthreads();

    // ---- cross-chunk argmin (8 chunks), loss per row ----
    {
        int row = tid >> 3, c = tid & 7;
        float v = sval[c][row];
        int   i = sidx[c][row];
        #pragma unroll
        for (int m = 1; m <= 4; m <<= 1) {
            float ov = __shfl_xor(v, m);
            int   oi = __shfl_xor(i, m);
            if (ov < v || (ov == v && oi < i)) { v = ov; i = oi; }
        }
        if (c == 0) {
            sfin[row]  = i;
            sloss[row] = sxsq[row] + v;   // ||x-e||^2 (bf16-dot precision)
        }
    }
    __syncthreads();

    // ---- loss partial (wave 0) ----
    if (tid < 64) {
        float l = sloss[tid];
        #pragma unroll
        for (int m = 1; m <= 32; m <<= 1) l += __shfl_xor(l, m);
        if (tid == 0) bsum[blockIdx.x] = l;
    }

    // ---- gather E[idx] (exact f32), coalesced 2KB per iteration ----
    #pragma unroll 4
    for (int p = 0; p < 32; ++p) {
        int elem = p * 512 + tid;
        int row = elem >> 8, d = elem & 255;
        int idx = sfin[row];
        outq[(m0 + row) * DIM + d] = E[idx * DIM + d];
    }
}

// ---- k3: reduce 256 partials -> loss ----------------------------------
__global__ __launch_bounds__(256) void k3_loss(
        const float* __restrict__ bsum, float* __restrict__ out) {
    __shared__ float ls[4];
    int tid = threadIdx.x;
    float s = bsum[tid];
    #pragma unroll
    for (int m = 1; m <= 32; m <<= 1) s += __shfl_xor(s, m);
    if ((tid & 63) == 0) ls[tid >> 6] = s;
    __syncthreads();
    if (tid == 0)
        out[0] = 1.25f * (ls[0] + ls[1] + ls[2] + ls[3]) * (1.0f / NUMEL);
}

extern "C" void kernel_launch(void* const* d_in, const int* in_sizes, int n_in,
                              void* d_out, int out_size, void* d_ws, size_t ws_size,
                              hipStream_t stream) {
    const float* X = (const float*)d_in[0];   // [8,2048,256] f32
    const float* E = (const float*)d_in[1];   // [1024,256]   f32
    float* out = (float*)d_out;               // [1 + 4194304] f32
    char* ws = (char*)d_ws;

    unsigned short* Ebf = (unsigned short*)ws;
    float* esq  = (float*)(ws + 524288);
    float* bsum = (float*)(ws + 528384);

    kprepE<<<NUM_EMB / 64, 256, 0, stream>>>(E, Ebf, esq);
    k1_main<<<ROWS / 64, 512, 0, stream>>>(X, Ebf, esq, E, out + 1, bsum);
    k3_loss<<<1, 256, 0, stream>>>(bsum, out);
}